// Round 1
// 68.436 us; speedup vs baseline: 1.0109x; 1.0109x over previous
//
#include <hip/hip_runtime.h>
#include <math.h>

// Problem constants (from reference):
//   vol: (B=1, C=1, W=96, H=96, D=64) float32, row-major -> vol[(x*96+y)*64+z]
//   out: (B,C,U=96,A=90,V=64) float32 -> out[(u*90+a)*64+v]
namespace {
constexpr int NA = 90, NU = 96, NV = 64, NW = 96, NH = 96, ND = 64;
constexpr int NRAY   = NA * NU;      // 8640
constexpr int NVOX   = NW * NH * ND; // 589824
constexpr int NENT   = 256;          // entries per ray (4 rounds x 64 lanes)
constexpr int CNTMAX = 208;          // gather cap (valid count <= ~196 structurally)
constexpr int TILE   = 8;            // rays per block = waves per block
constexpr int NBLK   = 1024;         // R15: exactly 4 blocks/CU (32 waves/CU)
constexpr int NEXTRA = NRAY - NBLK * TILE;  // 448 leftover rays, spread 1-per-block
}

// Compact branch-free f64 sincos (fdlibm kernel polys, |err| ~3e-16).
__device__ inline void sincos_poly(double xd, float* s, float* c)
{
    const double INV_PIO2 = 0.63661977236758134308;
    const double PIO2_HI  = 1.57079632679489655800e+00;
    const double PIO2_LO  = 6.12323399573676603587e-17;
    const double qd = rint(xd * INV_PIO2);            // 0,1,2 for xd in [0, 3.11)
    const double r  = (xd - qd * PIO2_HI) - qd * PIO2_LO;
    const double z  = r * r;
    const double sp = r + (r * z) * (-1.66666666666666324348e-01 + z *
                     ( 8.33333333332248946124e-03 + z *
                     (-1.98412698298579493134e-04 + z *
                     ( 2.75573137070700676789e-06 + z *
                     (-2.50507602534068634195e-08 + z *
                       1.58969099521155010221e-10)))));
    const double cp = 1.0 + z * (-0.5 + z *
                     ( 4.16666666666666019037e-02 + z *
                     (-1.38888888888741095749e-03 + z *
                     ( 2.48015872894767294178e-05 + z *
                     (-2.75573143513906633035e-07 + z *
                     ( 2.08757232129817482790e-09 + z *
                      -1.13596475577881948265e-11))))));
    const int q = (int)qd;
    const double sv = (q == 0) ? sp : ((q == 1) ? cp : -sp);
    const double cv = (q == 0) ? cp : ((q == 1) ? -sp : -cp);
    *s = (float)sv;
    *c = (float)cv;
}

// R15: one full ray (setup -> trace -> gather -> out write). Body is the
// validated R10/R14 code, unchanged; CONSUME places the prefetch-consume
// between trace and gather (first ray only) so the vmcnt wait lands after
// the trace VALU has hidden the HBM latency.
template <bool CONSUME>
__device__ __forceinline__ void do_ray(const float* __restrict__ vol,
                                       float* __restrict__ out,
                                       int2* __restrict__ myRow,
                                       const int ray, const int lane,
                                       const float4 wA, const float4 wB)
{
    const int a = ray / NU;
    const int u = ray - a * NU;

    const float EPSf = 1e-12f;
    const float INFp = __builtin_inff();
    const float DIAG = 1.41421356237309514547f;

    // ---------------- per-ray setup (wave-uniform) ----------------
    const float ang = (float)a * (float)(3.14159265358979323846 / 90.0);
    float dy, dx;
    sincos_poly((double)ang, &dy, &dx);        // dx = cos, dy = sin (f32-exact)
    const float uu = (float)u - 47.5f;
    const float x0 = __fmul_rn(-uu, dy);
    const float y0 = __fmul_rn( uu, dx);

    const float xmin = -47.5f, xmax = 47.5f;
    const float ymin = -47.5f, ymax = 47.5f;

    float tx0, tx1;
    {
        const bool par = fabsf(dx) < EPSf;
        const float safe = par ? 1.0f : dx;
        const float t0 = __fdiv_rn(xmin - x0, safe);
        const float t1 = __fdiv_rn(xmax - x0, safe);
        const float lo = fminf(t0, t1), hi = fmaxf(t0, t1);
        const bool inside = (x0 >= xmin) && (x0 <= xmax);
        tx0 = par ? (inside ? -INFp : INFp) : lo;
        tx1 = par ? (inside ?  INFp : -INFp) : hi;
    }
    float ty0, ty1;
    {
        const bool par = fabsf(dy) < EPSf;
        const float safe = par ? 1.0f : dy;
        const float t0 = __fdiv_rn(ymin - y0, safe);
        const float t1 = __fdiv_rn(ymax - y0, safe);
        const float lo = fminf(t0, t1), hi = fmaxf(t0, t1);
        const bool inside = (y0 >= ymin) && (y0 <= ymax);
        ty0 = par ? (inside ? -INFp : INFp) : lo;
        ty1 = par ? (inside ?  INFp : -INFp) : hi;
    }

    const float t_entry = fmaxf(tx0, ty0);
    const float t_exit  = fminf(tx1, ty1);
    const bool  alive0  = t_entry < t_exit;
    const float te  = alive0 ? t_entry : 0.0f;
    const float tex = alive0 ? t_exit  : 0.0f;

    const float xe = __fadd_rn(x0, __fmul_rn(te, dx));
    const float ye = __fadd_rn(y0, __fmul_rn(te, dy));
    const int i0 = (int)fminf(fmaxf(rintf(__fadd_rn(xe, 47.5f)), 0.0f), 95.0f);
    const int j0 = (int)fminf(fmaxf(rintf(__fadd_rn(ye, 47.5f)), 0.0f), 95.0f);

    const bool okx = fabsf(dx) > EPSf;
    const bool oky = fabsf(dy) > EPSf;
    const float inv_dx = okx ? __fdiv_rn(1.0f, dx) : 0.0f;
    const float inv_dy = oky ? __fdiv_rn(1.0f, dy) : 0.0f;
    const float wscale = __fdiv_rn(DIAG, fmaxf(fabsf(dx) + fabsf(dy), EPSf));
    const float tex_m_eps = __fadd_rn(tex, -EPSf);

    // APs of crossing times: Tx_k = Ax + k*px, Ty_m = Ay + m*py (absolute t).
    const float cx = (dx > 0.0f) ? -47.0f : -48.0f;
    const float cy = (dy > 0.0f) ? -47.0f : -48.0f;
    const float Ax = okx ? __fadd_rn(te, __fmul_rn(((float)i0 + cx) - xe, inv_dx)) : INFp;
    const float Ay = oky ? __fadd_rn(te, __fmul_rn(((float)j0 + cy) - ye, inv_dy)) : INFp;
    const float px = okx ? fabsf(inv_dx) : 0.0f;
    const float py = oky ? fabsf(inv_dy) : 0.0f;
    const int   si = (dx > 0.0f) ? 1 : -1;
    const int   sj = (dy > 0.0f) ? 1 : -1;

    const float inv_pq = __fdiv_rn(1.0f, px + py);
    const float Cc = Ay - Ax;

    // ---------------- lane-parallel trace: 4 rounds of 64 entries ----------------
    int cnt = 0;
    #pragma unroll
    for (int rnd = 0; rnd < 4; ++rnd) {
        const int n = (rnd << 6) + lane;
        const float nf = (float)n;

        float kf = __fmul_rn(__fmaf_rn(nf, py, Cc), inv_pq);
        kf = fminf(fmaxf(kf, 0.0f), nf);       // also collapses +-INF safely
        int k = (int)rintf(kf);

        // partition fixup: valid iff Tx_{k-1} <= Ty_{n-k} and Ty_{n-k-1} <= Tx_k.
        #pragma unroll
        for (int it = 0; it < 4; ++it) {
            const int m = n - k;
            const float Txk   = __fmaf_rn((float)k, px, Ax);
            const float Txkm1 = (k > 0) ? __fmaf_rn((float)(k - 1), px, Ax) : -INFp;
            const float Tyl   = __fmaf_rn((float)m, py, Ay);
            const float Tylm1 = (m > 0) ? __fmaf_rn((float)(m - 1), py, Ay) : -INFp;
            const bool dec = (Txkm1 > Tyl);
            const bool inc = (!dec) && (Tylm1 > Txk);
            k += inc ? 1 : (dec ? -1 : 0);
        }

        const int m = n - k;
        const float Txk   = __fmaf_rn((float)k, px, Ax);
        const float Txkm1 = (k > 0) ? __fmaf_rn((float)(k - 1), px, Ax) : -INFp;
        const float Tyl   = __fmaf_rn((float)m, py, Ay);
        const float Tylm1 = (m > 0) ? __fmaf_rn((float)(m - 1), py, Ay) : -INFp;

        const float Tn   = fminf(Txk, Tyl);                 // event ending segment n
        const float prev = fmaxf(te, fmaxf(Txkm1, Tylm1));  // event starting it
        const float dt   = __fadd_rn(fminf(Tn, tex), -fminf(prev, tex));
        const bool active = alive0 && (prev < tex_m_eps);
        float w = __fmul_rn(fmaxf(0.0f, dt), wscale);
        w = active ? w : 0.0f;

        const int ii = min(95, max(0, i0 + ((si > 0) ? k : -k)));
        const int jj = min(95, max(0, j0 + ((sj > 0) ? m : -m)));
        int2 e;
        e.x = (ii * NH + jj) << 8;             // BYTE offset into vol (256B rows)
        e.y = __float_as_int(w);
        myRow[n] = e;

        cnt += (int)__popcll(__ballot(active));
    }
    // cap is WAVE-UNIFORM (popc of ballots) -> SGPRs, no LDS, no barrier
    // (sEnt[wid] is wave-private; intra-wave LDS ordering via lgkmcnt).
    const int cap = min((cnt + 15) & ~15, CNTMAX);

    if (CONSUME) {
        // consume the prefetch results here: forces the loads to exist, and the
        // vmcnt wait lands AFTER the trace -> latency fully overlapped.
        asm volatile("" :: "v"(wA.x), "v"(wA.y), "v"(wA.z), "v"(wA.w),
                           "v"(wB.x), "v"(wB.y), "v"(wB.z), "v"(wB.w));
    }

    // ---------------- gather: quad-row (R10 structure, validated) ----------
    // Lane L: row-in-quad r=L>>4, 16B chunk sub=L&15. One dwordx4 per 4 entries
    // fetches four 256B vol rows.
    const int r   = lane >> 4;
    const int sub = lane & 15;
    const int subOff = sub << 4;

    const int2* __restrict__ eRow = myRow + r;       // entry n+r at [n]
    const char* __restrict__ vb   = (const char*)vol;

    float4 acc[4] = {{0,0,0,0}, {0,0,0,0}, {0,0,0,0}, {0,0,0,0}};
    for (int n = 0; n < cap; n += 16) {
        const int2 e0 = eRow[n];        // 4-address LDS broadcast (conflict-free)
        const int2 e1 = eRow[n + 4];
        const int2 e2 = eRow[n + 8];
        const int2 e3 = eRow[n + 12];
        const float4 v0 = *(const float4*)(vb + (e0.x + subOff));  // 4 rows/instr
        const float4 v1 = *(const float4*)(vb + (e1.x + subOff));
        const float4 v2 = *(const float4*)(vb + (e2.x + subOff));
        const float4 v3 = *(const float4*)(vb + (e3.x + subOff));
        const float w0 = __int_as_float(e0.y);
        const float w1 = __int_as_float(e1.y);
        const float w2 = __int_as_float(e2.y);
        const float w3 = __int_as_float(e3.y);
        acc[0].x = fmaf(w0, v0.x, acc[0].x); acc[0].y = fmaf(w0, v0.y, acc[0].y);
        acc[0].z = fmaf(w0, v0.z, acc[0].z); acc[0].w = fmaf(w0, v0.w, acc[0].w);
        acc[1].x = fmaf(w1, v1.x, acc[1].x); acc[1].y = fmaf(w1, v1.y, acc[1].y);
        acc[1].z = fmaf(w1, v1.z, acc[1].z); acc[1].w = fmaf(w1, v1.w, acc[1].w);
        acc[2].x = fmaf(w2, v2.x, acc[2].x); acc[2].y = fmaf(w2, v2.y, acc[2].y);
        acc[2].z = fmaf(w2, v2.z, acc[2].z); acc[2].w = fmaf(w2, v2.w, acc[2].w);
        acc[3].x = fmaf(w3, v3.x, acc[3].x); acc[3].y = fmaf(w3, v3.y, acc[3].y);
        acc[3].z = fmaf(w3, v3.z, acc[3].z); acc[3].w = fmaf(w3, v3.w, acc[3].w);
    }

    float sx = (acc[0].x + acc[1].x) + (acc[2].x + acc[3].x);
    float sy = (acc[0].y + acc[1].y) + (acc[2].y + acc[3].y);
    float sz = (acc[0].z + acc[1].z) + (acc[2].z + acc[3].z);
    float sw = (acc[0].w + acc[1].w) + (acc[2].w + acc[3].w);

    // reduce across the 4 row groups: lanes {sub, 16+sub, 32+sub, 48+sub}
    sx += __shfl_xor(sx, 16, 64);  sy += __shfl_xor(sy, 16, 64);
    sz += __shfl_xor(sz, 16, 64);  sw += __shfl_xor(sw, 16, 64);
    sx += __shfl_xor(sx, 32, 64);  sy += __shfl_xor(sy, 32, 64);
    sz += __shfl_xor(sz, 32, 64);  sw += __shfl_xor(sw, 32, 64);

    if (lane < 16) {
        float4 res; res.x = sx; res.y = sy; res.z = sz; res.w = sw;
        *(float4*)(out + (u * NA + a) * NV + (sub << 2)) = res;  // 256B coalesced
    }
}

// R15: wave-balanced persistent grid. Previous grid (1080 blocks, 8 waves)
// needed 8640 wave-slots but the chip has exactly 1024 SIMDs x 8 = 8192:
// 56 CUs ran a serialized 5th block (10 rays/SIMD vs 8.44 avg, ~18% tail).
// Now: 1024 blocks (4/CU exactly); wave (bid,wid) does ray bid*8+wid, and
// the 448 leftover rays go one-per-block to blocks 0..447 on wave
// (bid+(bid>>8))&7 -- under the round-robin block->CU map (CU ~ bid%256,
// blocks c and c+256 share a CU) the two extras a CU gets land on DIFFERENT
// SIMDs. Max SIMD load drops 10 -> 9 ray-units (avg 8.4375).
__global__ __launch_bounds__(512)
void siddon_fused(const float* __restrict__ vol, float* __restrict__ out)
{
    __shared__ int2 sEnt[TILE][NENT];  // .x = BYTE offset of vol row, .y = weight bits

    const int tid  = threadIdx.x;
    const int wid  = tid >> 6;         // wave index in block
    const int lane = tid & 63;
    const int bid  = blockIdx.x;

    // ---- early vol prefetch (issued before setup; consumed after trace) ----
    // 128 groups of 8 blocks; each group sweeps 1152 float4 chunks (covers vol
    // exactly across the grid; 2 loads/thread cover 1024/1152 ~ 89% of each
    // group -- enough to warm L2/L3 after the harness's 268MB poison sweep).
    float4 wA = {0, 0, 0, 0}, wB = {0, 0, 0, 0};
    {
        const int nchunks = NVOX / 4;          // 147456 float4 lines of vol
        const int base = (bid >> 3) * 1152;
        const int iA = base + tid;
        const int iB = base + 512 + tid;
        const int hi = min(base + 1152, nchunks);
        if (iA < hi) wA = *(const float4*)(vol + (size_t)iA * 4);
        if (iB < hi) wB = *(const float4*)(vol + (size_t)iB * 4);
    }

    int2* __restrict__ myRow = &sEnt[wid][0];

    const int ray0 = bid * TILE + wid;             // rays 0..8191
    do_ray<true>(vol, out, myRow, ray0, lane, wA, wB);

    // leftover rays 8192..8639: one per block (bid<448), on a wave chosen so
    // the two extras per CU land on different SIMDs.
    if (bid < NEXTRA && wid == ((bid + (bid >> 8)) & 7)) {
        do_ray<false>(vol, out, myRow, NBLK * TILE + bid, lane, wA, wB);
    }
}

extern "C" void kernel_launch(void* const* d_in, const int* in_sizes, int n_in,
                              void* d_out, int out_size, void* d_ws, size_t ws_size,
                              hipStream_t stream) {
    const float* vol = (const float*)d_in[0];
    float* out = (float*)d_out;
    hipLaunchKernelGGL(siddon_fused, dim3(NBLK), dim3(512), 0, stream, vol, out);
}

// Round 2
// 68.370 us; speedup vs baseline: 1.0119x; 1.0010x over previous
//
#include <hip/hip_runtime.h>
#include <math.h>

// Problem constants (from reference):
//   vol: (B=1, C=1, W=96, H=96, D=64) float32, row-major -> vol[(x*96+y)*64+z]
//   out: (B,C,U=96,A=90,V=64) float32 -> out[(u*90+a)*64+v]
namespace {
constexpr int NA = 90, NU = 96, NV = 64, NW = 96, NH = 96, ND = 64;
constexpr int NRAY   = NA * NU;      // 8640
constexpr int NENT   = 256;          // entries per ray (4 rounds x 64 lanes)
constexpr int CNTMAX = 208;          // gather cap (valid count <= ~196 structurally)
constexpr int TILE   = 8;            // rays per block = waves per block
constexpr int NBLK   = 1024;         // exactly 4 blocks/CU (32 waves/CU) IF vgpr<=64
constexpr int NEXTRA = NRAY - NBLK * TILE;  // 448 leftover rays, spread 1-per-block
}

// Compact branch-free f64 sincos (fdlibm kernel polys, |err| ~3e-16).
__device__ inline void sincos_poly(double xd, float* s, float* c)
{
    const double INV_PIO2 = 0.63661977236758134308;
    const double PIO2_HI  = 1.57079632679489655800e+00;
    const double PIO2_LO  = 6.12323399573676603587e-17;
    const double qd = rint(xd * INV_PIO2);            // 0,1,2 for xd in [0, 3.11)
    const double r  = (xd - qd * PIO2_HI) - qd * PIO2_LO;
    const double z  = r * r;
    const double sp = r + (r * z) * (-1.66666666666666324348e-01 + z *
                     ( 8.33333333332248946124e-03 + z *
                     (-1.98412698298579493134e-04 + z *
                     ( 2.75573137070700676789e-06 + z *
                     (-2.50507602534068634195e-08 + z *
                       1.58969099521155010221e-10)))));
    const double cp = 1.0 + z * (-0.5 + z *
                     ( 4.16666666666666019037e-02 + z *
                     (-1.38888888888741095749e-03 + z *
                     ( 2.48015872894767294178e-05 + z *
                     (-2.75573143513906633035e-07 + z *
                     ( 2.08757232129817482790e-09 + z *
                      -1.13596475577881948265e-11))))));
    const int q = (int)qd;
    const double sv = (q == 0) ? sp : ((q == 1) ? cp : -sp);
    const double cv = (q == 0) ? cp : ((q == 1) ? -sp : -cp);
    *s = (float)sv;
    *c = (float)cv;
}

// R16: hoist wave-uniform per-ray scalars to SGPRs. All setup values derive
// from `ray` (uniform per wave: bid*TILE+wid, wid=tid>>6), so every lane holds
// identical bits -- readfirstlane is semantics-preserving and moves the live
// range out of the VGPR file (frees ~14 phase-crossing VGPRs).
__device__ __forceinline__ float rflf(float x) {
    return __int_as_float(__builtin_amdgcn_readfirstlane(__float_as_int(x)));
}
__device__ __forceinline__ int rfli(int x) {
    return __builtin_amdgcn_readfirstlane(x);
}

// One full ray (setup -> trace -> gather -> out write). Body is the validated
// R10 structure; R16 removes the prefetch plumbing and SGPR-hoists uniforms.
__device__ __forceinline__ void do_ray(const float* __restrict__ vol,
                                       float* __restrict__ out,
                                       int2* __restrict__ myRow,
                                       const int ray, const int lane)
{
    const int a = ray / NU;
    const int u = ray - a * NU;

    const float EPSf = 1e-12f;
    const float INFp = __builtin_inff();
    const float DIAG = 1.41421356237309514547f;

    // ---------------- per-ray setup (wave-uniform) ----------------
    const float ang = (float)a * (float)(3.14159265358979323846 / 90.0);
    float dy, dx;
    sincos_poly((double)ang, &dy, &dx);        // dx = cos, dy = sin (f32-exact)
    const float uu = (float)u - 47.5f;
    const float x0 = __fmul_rn(-uu, dy);
    const float y0 = __fmul_rn( uu, dx);

    const float xmin = -47.5f, xmax = 47.5f;
    const float ymin = -47.5f, ymax = 47.5f;

    float tx0, tx1;
    {
        const bool par = fabsf(dx) < EPSf;
        const float safe = par ? 1.0f : dx;
        const float t0 = __fdiv_rn(xmin - x0, safe);
        const float t1 = __fdiv_rn(xmax - x0, safe);
        const float lo = fminf(t0, t1), hi = fmaxf(t0, t1);
        const bool inside = (x0 >= xmin) && (x0 <= xmax);
        tx0 = par ? (inside ? -INFp : INFp) : lo;
        tx1 = par ? (inside ?  INFp : -INFp) : hi;
    }
    float ty0, ty1;
    {
        const bool par = fabsf(dy) < EPSf;
        const float safe = par ? 1.0f : dy;
        const float t0 = __fdiv_rn(ymin - y0, safe);
        const float t1 = __fdiv_rn(ymax - y0, safe);
        const float lo = fminf(t0, t1), hi = fmaxf(t0, t1);
        const bool inside = (y0 >= ymin) && (y0 <= ymax);
        ty0 = par ? (inside ? -INFp : INFp) : lo;
        ty1 = par ? (inside ?  INFp : -INFp) : hi;
    }

    const float t_entry = fmaxf(tx0, ty0);
    const float t_exit  = fminf(tx1, ty1);
    const bool  alive0  = t_entry < t_exit;
    const float te  = rflf(alive0 ? t_entry : 0.0f);
    const float tex = rflf(alive0 ? t_exit  : 0.0f);

    const float xe = __fadd_rn(x0, __fmul_rn(te, dx));
    const float ye = __fadd_rn(y0, __fmul_rn(te, dy));
    const int i0 = rfli((int)fminf(fmaxf(rintf(__fadd_rn(xe, 47.5f)), 0.0f), 95.0f));
    const int j0 = rfli((int)fminf(fmaxf(rintf(__fadd_rn(ye, 47.5f)), 0.0f), 95.0f));

    const bool okx = fabsf(dx) > EPSf;
    const bool oky = fabsf(dy) > EPSf;
    const float inv_dx = okx ? __fdiv_rn(1.0f, dx) : 0.0f;
    const float inv_dy = oky ? __fdiv_rn(1.0f, dy) : 0.0f;
    const float wscale = rflf(__fdiv_rn(DIAG, fmaxf(fabsf(dx) + fabsf(dy), EPSf)));
    // When !alive0: te=tex=0 => prev = max(0,..) >= 0 > tex-eps => inactive,
    // so alive0 needs no separate test in the trace loop.
    const float tex_m_eps = rflf(__fadd_rn(tex, -EPSf));

    // APs of crossing times: Tx_k = Ax + k*px, Ty_m = Ay + m*py (absolute t).
    const float cx = (dx > 0.0f) ? -47.0f : -48.0f;
    const float cy = (dy > 0.0f) ? -47.0f : -48.0f;
    const float Ax = rflf(okx ? __fadd_rn(te, __fmul_rn(((float)i0 + cx) - xe, inv_dx)) : INFp);
    const float Ay = rflf(oky ? __fadd_rn(te, __fmul_rn(((float)j0 + cy) - ye, inv_dy)) : INFp);
    const float px = rflf(okx ? fabsf(inv_dx) : 0.0f);
    const float py = rflf(oky ? fabsf(inv_dy) : 0.0f);
    const int   si = rfli((dx > 0.0f) ? 1 : -1);
    const int   sj = rfli((dy > 0.0f) ? 1 : -1);

    const float inv_pq = rflf(__fdiv_rn(1.0f, px + py));
    const float Cc = rflf(Ay - Ax);

    // ---------------- lane-parallel trace: 4 rounds of 64 entries ----------------
    int cnt = 0;
    #pragma unroll
    for (int rnd = 0; rnd < 4; ++rnd) {
        const int n = (rnd << 6) + lane;
        const float nf = (float)n;

        float kf = __fmul_rn(__fmaf_rn(nf, py, Cc), inv_pq);
        kf = fminf(fmaxf(kf, 0.0f), nf);       // also collapses +-INF safely
        int k = (int)rintf(kf);

        // partition fixup: valid iff Tx_{k-1} <= Ty_{n-k} and Ty_{n-k-1} <= Tx_k.
        #pragma unroll
        for (int it = 0; it < 4; ++it) {
            const int m = n - k;
            const float Txk   = __fmaf_rn((float)k, px, Ax);
            const float Txkm1 = (k > 0) ? __fmaf_rn((float)(k - 1), px, Ax) : -INFp;
            const float Tyl   = __fmaf_rn((float)m, py, Ay);
            const float Tylm1 = (m > 0) ? __fmaf_rn((float)(m - 1), py, Ay) : -INFp;
            const bool dec = (Txkm1 > Tyl);
            const bool inc = (!dec) && (Tylm1 > Txk);
            k += inc ? 1 : (dec ? -1 : 0);
        }

        const int m = n - k;
        const float Txk   = __fmaf_rn((float)k, px, Ax);
        const float Txkm1 = (k > 0) ? __fmaf_rn((float)(k - 1), px, Ax) : -INFp;
        const float Tyl   = __fmaf_rn((float)m, py, Ay);
        const float Tylm1 = (m > 0) ? __fmaf_rn((float)(m - 1), py, Ay) : -INFp;

        const float Tn   = fminf(Txk, Tyl);                 // event ending segment n
        const float prev = fmaxf(te, fmaxf(Txkm1, Tylm1));  // event starting it
        const float dt   = __fadd_rn(fminf(Tn, tex), -fminf(prev, tex));
        const bool active = (prev < tex_m_eps);
        float w = __fmul_rn(fmaxf(0.0f, dt), wscale);
        w = active ? w : 0.0f;

        const int ii = min(95, max(0, i0 + ((si > 0) ? k : -k)));
        const int jj = min(95, max(0, j0 + ((sj > 0) ? m : -m)));
        int2 e;
        e.x = (ii * NH + jj) << 8;             // BYTE offset into vol (256B rows)
        e.y = __float_as_int(w);
        myRow[n] = e;

        cnt += (int)__popcll(__ballot(active));
    }
    // cap is WAVE-UNIFORM (popc of ballots) -> SGPRs, no LDS, no barrier
    // (sEnt[wid] is wave-private; intra-wave LDS ordering via lgkmcnt).
    const int cap = min((cnt + 15) & ~15, CNTMAX);

    // ---------------- gather: quad-row (R10 structure, validated) ----------
    // Lane L: row-in-quad r=L>>4, 16B chunk sub=L&15. One dwordx4 per 4 entries
    // fetches four 256B vol rows.
    const int r   = lane >> 4;
    const int sub = lane & 15;
    const int subOff = sub << 4;

    const int2* __restrict__ eRow = myRow + r;       // entry n+r at [n]
    const char* __restrict__ vb   = (const char*)vol;

    float4 acc[4] = {{0,0,0,0}, {0,0,0,0}, {0,0,0,0}, {0,0,0,0}};
    for (int n = 0; n < cap; n += 16) {
        const int2 e0 = eRow[n];        // 4-address LDS broadcast (conflict-free)
        const int2 e1 = eRow[n + 4];
        const int2 e2 = eRow[n + 8];
        const int2 e3 = eRow[n + 12];
        const float4 v0 = *(const float4*)(vb + (e0.x + subOff));  // 4 rows/instr
        const float4 v1 = *(const float4*)(vb + (e1.x + subOff));
        const float4 v2 = *(const float4*)(vb + (e2.x + subOff));
        const float4 v3 = *(const float4*)(vb + (e3.x + subOff));
        const float w0 = __int_as_float(e0.y);
        const float w1 = __int_as_float(e1.y);
        const float w2 = __int_as_float(e2.y);
        const float w3 = __int_as_float(e3.y);
        acc[0].x = fmaf(w0, v0.x, acc[0].x); acc[0].y = fmaf(w0, v0.y, acc[0].y);
        acc[0].z = fmaf(w0, v0.z, acc[0].z); acc[0].w = fmaf(w0, v0.w, acc[0].w);
        acc[1].x = fmaf(w1, v1.x, acc[1].x); acc[1].y = fmaf(w1, v1.y, acc[1].y);
        acc[1].z = fmaf(w1, v1.z, acc[1].z); acc[1].w = fmaf(w1, v1.w, acc[1].w);
        acc[2].x = fmaf(w2, v2.x, acc[2].x); acc[2].y = fmaf(w2, v2.y, acc[2].y);
        acc[2].z = fmaf(w2, v2.z, acc[2].z); acc[2].w = fmaf(w2, v2.w, acc[2].w);
        acc[3].x = fmaf(w3, v3.x, acc[3].x); acc[3].y = fmaf(w3, v3.y, acc[3].y);
        acc[3].z = fmaf(w3, v3.z, acc[3].z); acc[3].w = fmaf(w3, v3.w, acc[3].w);
    }

    float sx = (acc[0].x + acc[1].x) + (acc[2].x + acc[3].x);
    float sy = (acc[0].y + acc[1].y) + (acc[2].y + acc[3].y);
    float sz = (acc[0].z + acc[1].z) + (acc[2].z + acc[3].z);
    float sw = (acc[0].w + acc[1].w) + (acc[2].w + acc[3].w);

    // reduce across the 4 row groups: lanes {sub, 16+sub, 32+sub, 48+sub}
    sx += __shfl_xor(sx, 16, 64);  sy += __shfl_xor(sy, 16, 64);
    sz += __shfl_xor(sz, 16, 64);  sw += __shfl_xor(sw, 16, 64);
    sx += __shfl_xor(sx, 32, 64);  sy += __shfl_xor(sy, 32, 64);
    sz += __shfl_xor(sz, 32, 64);  sw += __shfl_xor(sw, 32, 64);

    if (lane < 16) {
        float4 res; res.x = sx; res.y = sy; res.z = sz; res.w = sw;
        *(float4*)(out + (u * NA + a) * NV + (sub << 2)) = res;  // 256B coalesced
    }
}

// R16: force the 8-waves/SIMD occupancy tier. Occupancy steps at VGPR=64/128
// (m69); the R15 kernel likely sat in the 65-128 band -> only 4 waves/SIMD
// (2 blocks/CU), halving latency hiding for the gather's LDS->VMEM->FMA chain.
// __launch_bounds__(512, 8) caps VGPR at 64; SGPR-hoisted uniforms + dropped
// prefetch make that budget feasible. Grid/balance logic unchanged from R15.
__global__ __launch_bounds__(512, 8)
void siddon_fused(const float* __restrict__ vol, float* __restrict__ out)
{
    __shared__ int2 sEnt[TILE][NENT];  // .x = BYTE offset of vol row, .y = weight bits

    const int tid  = threadIdx.x;
    const int wid  = tid >> 6;         // wave index in block
    const int lane = tid & 63;
    const int bid  = blockIdx.x;

    int2* __restrict__ myRow = &sEnt[wid][0];

    const int ray0 = bid * TILE + wid;             // rays 0..8191
    do_ray(vol, out, myRow, ray0, lane);

    // leftover rays 8192..8639: one per block (bid<448), on a wave chosen so
    // the two extras per CU land on different SIMDs.
    if (bid < NEXTRA && wid == ((bid + (bid >> 8)) & 7)) {
        do_ray(vol, out, myRow, NBLK * TILE + bid, lane);
    }
}

extern "C" void kernel_launch(void* const* d_in, const int* in_sizes, int n_in,
                              void* d_out, int out_size, void* d_ws, size_t ws_size,
                              hipStream_t stream) {
    const float* vol = (const float*)d_in[0];
    float* out = (float*)d_out;
    hipLaunchKernelGGL(siddon_fused, dim3(NBLK), dim3(512), 0, stream, vol, out);
}

// Round 4
// 67.143 us; speedup vs baseline: 1.0304x; 1.0183x over previous
//
#include <hip/hip_runtime.h>
#include <math.h>

// R17-resubmit: identical to previous round's source; the bench infra failed
// ("container failed twice") before compiling it, so the variable-round-count
// hypothesis is still untested.
//
// Problem constants (from reference):
//   vol: (B=1, C=1, W=96, H=96, D=64) float32, row-major -> vol[(x*96+y)*64+z]
//   out: (B,C,U=96,A=90,V=64) float32 -> out[(u*90+a)*64+v]
namespace {
constexpr int NA = 90, NU = 96, NV = 64, NW = 96, NH = 96, ND = 64;
constexpr int NRAY   = NA * NU;      // 8640
constexpr int NENT   = 256;          // entries per ray (<=4 rounds x 64 lanes)
constexpr int CNTMAX = 208;          // gather cap (valid count <= ~196 structurally)
constexpr int TILE   = 8;            // rays per block = waves per block
constexpr int NBLK   = 1024;         // exactly 4 blocks/CU (32 waves/CU), vgpr<=64
constexpr int NEXTRA = NRAY - NBLK * TILE;  // 448 leftover rays, spread 1-per-block
}

// Compact branch-free f64 sincos (fdlibm kernel polys, |err| ~3e-16).
__device__ inline void sincos_poly(double xd, float* s, float* c)
{
    const double INV_PIO2 = 0.63661977236758134308;
    const double PIO2_HI  = 1.57079632679489655800e+00;
    const double PIO2_LO  = 6.12323399573676603587e-17;
    const double qd = rint(xd * INV_PIO2);            // 0,1,2 for xd in [0, 3.11)
    const double r  = (xd - qd * PIO2_HI) - qd * PIO2_LO;
    const double z  = r * r;
    const double sp = r + (r * z) * (-1.66666666666666324348e-01 + z *
                     ( 8.33333333332248946124e-03 + z *
                     (-1.98412698298579493134e-04 + z *
                     ( 2.75573137070700676789e-06 + z *
                     (-2.50507602534068634195e-08 + z *
                       1.58969099521155010221e-10)))));
    const double cp = 1.0 + z * (-0.5 + z *
                     ( 4.16666666666666019037e-02 + z *
                     (-1.38888888888741095749e-03 + z *
                     ( 2.48015872894767294178e-05 + z *
                     (-2.75573143513906633035e-07 + z *
                     ( 2.08757232129817482790e-09 + z *
                      -1.13596475577881948265e-11))))));
    const int q = (int)qd;
    const double sv = (q == 0) ? sp : ((q == 1) ? cp : -sp);
    const double cv = (q == 0) ? cp : ((q == 1) ? -sp : -cp);
    *s = (float)sv;
    *c = (float)cv;
}

// Wave-uniform scalars -> SGPRs (R16; semantics-preserving, all lanes identical).
__device__ __forceinline__ float rflf(float x) {
    return __int_as_float(__builtin_amdgcn_readfirstlane(__float_as_int(x)));
}
__device__ __forceinline__ int rfli(int x) {
    return __builtin_amdgcn_readfirstlane(x);
}

// One full ray (setup -> trace -> gather -> out write).
// R17: the trace runs a VARIABLE number of 64-entry rounds. The valid-segment
// count has a closed form (1 + #x-crossings + #y-crossings before t_exit);
// the fixed 4-round loop spent ~52% of trace VALU on provably-inactive
// entries (avg 122 valid of 256) and ran full-length on dead rays. A +2
// segment margin makes fp rounding only ever ADD a spare round; `prev_n` is
// monotone in n, so all entries in skipped rounds are inactive, and `cap`
// still derives from ballots over EXECUTED rounds -> gather never touches
// unwritten LDS (cap <= rounds*64 structurally).
__device__ __forceinline__ void do_ray(const float* __restrict__ vol,
                                       float* __restrict__ out,
                                       int2* __restrict__ myRow,
                                       const int ray, const int lane)
{
    const int a = ray / NU;
    const int u = ray - a * NU;

    const float EPSf = 1e-12f;
    const float INFp = __builtin_inff();
    const float DIAG = 1.41421356237309514547f;

    // ---------------- per-ray setup (wave-uniform) ----------------
    const float ang = (float)a * (float)(3.14159265358979323846 / 90.0);
    float dy, dx;
    sincos_poly((double)ang, &dy, &dx);        // dx = cos, dy = sin (f32-exact)
    const float uu = (float)u - 47.5f;
    const float x0 = __fmul_rn(-uu, dy);
    const float y0 = __fmul_rn( uu, dx);

    const float xmin = -47.5f, xmax = 47.5f;
    const float ymin = -47.5f, ymax = 47.5f;

    float tx0, tx1;
    {
        const bool par = fabsf(dx) < EPSf;
        const float safe = par ? 1.0f : dx;
        const float t0 = __fdiv_rn(xmin - x0, safe);
        const float t1 = __fdiv_rn(xmax - x0, safe);
        const float lo = fminf(t0, t1), hi = fmaxf(t0, t1);
        const bool inside = (x0 >= xmin) && (x0 <= xmax);
        tx0 = par ? (inside ? -INFp : INFp) : lo;
        tx1 = par ? (inside ?  INFp : -INFp) : hi;
    }
    float ty0, ty1;
    {
        const bool par = fabsf(dy) < EPSf;
        const float safe = par ? 1.0f : dy;
        const float t0 = __fdiv_rn(ymin - y0, safe);
        const float t1 = __fdiv_rn(ymax - y0, safe);
        const float lo = fminf(t0, t1), hi = fmaxf(t0, t1);
        const bool inside = (y0 >= ymin) && (y0 <= ymax);
        ty0 = par ? (inside ? -INFp : INFp) : lo;
        ty1 = par ? (inside ?  INFp : -INFp) : hi;
    }

    const float t_entry = fmaxf(tx0, ty0);
    const float t_exit  = fminf(tx1, ty1);
    const bool  alive0  = t_entry < t_exit;
    const float te  = rflf(alive0 ? t_entry : 0.0f);
    const float tex = rflf(alive0 ? t_exit  : 0.0f);

    const float xe = __fadd_rn(x0, __fmul_rn(te, dx));
    const float ye = __fadd_rn(y0, __fmul_rn(te, dy));
    const int i0 = rfli((int)fminf(fmaxf(rintf(__fadd_rn(xe, 47.5f)), 0.0f), 95.0f));
    const int j0 = rfli((int)fminf(fmaxf(rintf(__fadd_rn(ye, 47.5f)), 0.0f), 95.0f));

    const bool okx = fabsf(dx) > EPSf;
    const bool oky = fabsf(dy) > EPSf;
    const float inv_dx = okx ? __fdiv_rn(1.0f, dx) : 0.0f;
    const float inv_dy = oky ? __fdiv_rn(1.0f, dy) : 0.0f;
    const float wscale = rflf(__fdiv_rn(DIAG, fmaxf(fabsf(dx) + fabsf(dy), EPSf)));
    // When !alive0: te=tex=0 => prev >= 0 > tex-eps => inactive automatically.
    const float tex_m_eps = rflf(__fadd_rn(tex, -EPSf));

    // APs of crossing times: Tx_k = Ax + k*px, Ty_m = Ay + m*py (absolute t).
    const float cx = (dx > 0.0f) ? -47.0f : -48.0f;
    const float cy = (dy > 0.0f) ? -47.0f : -48.0f;
    const float Ax = rflf(okx ? __fadd_rn(te, __fmul_rn(((float)i0 + cx) - xe, inv_dx)) : INFp);
    const float Ay = rflf(oky ? __fadd_rn(te, __fmul_rn(((float)j0 + cy) - ye, inv_dy)) : INFp);
    const float px = rflf(okx ? fabsf(inv_dx) : 0.0f);
    const float py = rflf(oky ? fabsf(inv_dy) : 0.0f);
    const int   si = rfli((dx > 0.0f) ? 1 : -1);
    const int   sj = rfli((dy > 0.0f) ? 1 : -1);

    const float inv_pq = rflf(__fdiv_rn(1.0f, px + py));
    const float Cc = rflf(Ay - Ax);

    // ---- R17: closed-form valid-segment count -> variable round count ----
    // #active = 1 + #{k>=0: Ax+k*px < tex-eps} + #{m>=0: Ay+m*py < tex-eps}.
    // floor(Q)+1 form overcounts on integral Q (safe direction); +2 margin.
    int nx = 0, ny = 0;
    if (okx) {  // px >= ~1 when okx, division safe
        const float Qx = __fdiv_rn(tex_m_eps - Ax, px);
        nx = min(96, max(0, (int)floorf(Qx) + 1));
    }
    if (oky) {
        const float Qy = __fdiv_rn(tex_m_eps - Ay, py);
        ny = min(96, max(0, (int)floorf(Qy) + 1));
    }
    const int nvalid = 1 + nx + ny;                     // <= 193 structurally
    const int rounds = rfli(alive0 ? min(4, (nvalid + 2 + 63) >> 6) : 0);

    // ---------------- lane-parallel trace: `rounds` rounds of 64 entries ----
    int cnt = 0;
    for (int rnd = 0; rnd < rounds; ++rnd) {
        const int n = (rnd << 6) + lane;
        const float nf = (float)n;

        float kf = __fmul_rn(__fmaf_rn(nf, py, Cc), inv_pq);
        kf = fminf(fmaxf(kf, 0.0f), nf);       // also collapses +-INF safely
        int k = (int)rintf(kf);

        // partition fixup: valid iff Tx_{k-1} <= Ty_{n-k} and Ty_{n-k-1} <= Tx_k.
        #pragma unroll
        for (int it = 0; it < 4; ++it) {
            const int m = n - k;
            const float Txk   = __fmaf_rn((float)k, px, Ax);
            const float Txkm1 = (k > 0) ? __fmaf_rn((float)(k - 1), px, Ax) : -INFp;
            const float Tyl   = __fmaf_rn((float)m, py, Ay);
            const float Tylm1 = (m > 0) ? __fmaf_rn((float)(m - 1), py, Ay) : -INFp;
            const bool dec = (Txkm1 > Tyl);
            const bool inc = (!dec) && (Tylm1 > Txk);
            k += inc ? 1 : (dec ? -1 : 0);
        }

        const int m = n - k;
        const float Txk   = __fmaf_rn((float)k, px, Ax);
        const float Txkm1 = (k > 0) ? __fmaf_rn((float)(k - 1), px, Ax) : -INFp;
        const float Tyl   = __fmaf_rn((float)m, py, Ay);
        const float Tylm1 = (m > 0) ? __fmaf_rn((float)(m - 1), py, Ay) : -INFp;

        const float Tn   = fminf(Txk, Tyl);                 // event ending segment n
        const float prev = fmaxf(te, fmaxf(Txkm1, Tylm1));  // event starting it
        const float dt   = __fadd_rn(fminf(Tn, tex), -fminf(prev, tex));
        const bool active = (prev < tex_m_eps);
        float w = __fmul_rn(fmaxf(0.0f, dt), wscale);
        w = active ? w : 0.0f;

        const int ii = min(95, max(0, i0 + ((si > 0) ? k : -k)));
        const int jj = min(95, max(0, j0 + ((sj > 0) ? m : -m)));
        int2 e;
        e.x = (ii * NH + jj) << 8;             // BYTE offset into vol (256B rows)
        e.y = __float_as_int(w);
        myRow[n] = e;

        cnt += (int)__popcll(__ballot(active));
    }
    // cap is WAVE-UNIFORM (popc of ballots over EXECUTED rounds) -> SGPRs;
    // cnt <= rounds*64, so cap (rounded to 16) never exceeds written entries.
    const int cap = min((cnt + 15) & ~15, CNTMAX);

    // ---------------- gather: quad-row (R10 structure, validated) ----------
    // Lane L: row-in-quad r=L>>4, 16B chunk sub=L&15. One dwordx4 per 4 entries
    // fetches four 256B vol rows.
    const int r   = lane >> 4;
    const int sub = lane & 15;
    const int subOff = sub << 4;

    const int2* __restrict__ eRow = myRow + r;       // entry n+r at [n]
    const char* __restrict__ vb   = (const char*)vol;

    float4 acc[4] = {{0,0,0,0}, {0,0,0,0}, {0,0,0,0}, {0,0,0,0}};
    for (int n = 0; n < cap; n += 16) {
        const int2 e0 = eRow[n];        // 4-address LDS broadcast (conflict-free)
        const int2 e1 = eRow[n + 4];
        const int2 e2 = eRow[n + 8];
        const int2 e3 = eRow[n + 12];
        const float4 v0 = *(const float4*)(vb + (e0.x + subOff));  // 4 rows/instr
        const float4 v1 = *(const float4*)(vb + (e1.x + subOff));
        const float4 v2 = *(const float4*)(vb + (e2.x + subOff));
        const float4 v3 = *(const float4*)(vb + (e3.x + subOff));
        const float w0 = __int_as_float(e0.y);
        const float w1 = __int_as_float(e1.y);
        const float w2 = __int_as_float(e2.y);
        const float w3 = __int_as_float(e3.y);
        acc[0].x = fmaf(w0, v0.x, acc[0].x); acc[0].y = fmaf(w0, v0.y, acc[0].y);
        acc[0].z = fmaf(w0, v0.z, acc[0].z); acc[0].w = fmaf(w0, v0.w, acc[0].w);
        acc[1].x = fmaf(w1, v1.x, acc[1].x); acc[1].y = fmaf(w1, v1.y, acc[1].y);
        acc[1].z = fmaf(w1, v1.z, acc[1].z); acc[1].w = fmaf(w1, v1.w, acc[1].w);
        acc[2].x = fmaf(w2, v2.x, acc[2].x); acc[2].y = fmaf(w2, v2.y, acc[2].y);
        acc[2].z = fmaf(w2, v2.z, acc[2].z); acc[2].w = fmaf(w2, v2.w, acc[2].w);
        acc[3].x = fmaf(w3, v3.x, acc[3].x); acc[3].y = fmaf(w3, v3.y, acc[3].y);
        acc[3].z = fmaf(w3, v3.z, acc[3].z); acc[3].w = fmaf(w3, v3.w, acc[3].w);
    }

    float sx = (acc[0].x + acc[1].x) + (acc[2].x + acc[3].x);
    float sy = (acc[0].y + acc[1].y) + (acc[2].y + acc[3].y);
    float sz = (acc[0].z + acc[1].z) + (acc[2].z + acc[3].z);
    float sw = (acc[0].w + acc[1].w) + (acc[2].w + acc[3].w);

    // reduce across the 4 row groups: lanes {sub, 16+sub, 32+sub, 48+sub}
    sx += __shfl_xor(sx, 16, 64);  sy += __shfl_xor(sy, 16, 64);
    sz += __shfl_xor(sz, 16, 64);  sw += __shfl_xor(sw, 16, 64);
    sx += __shfl_xor(sx, 32, 64);  sy += __shfl_xor(sy, 32, 64);
    sz += __shfl_xor(sz, 32, 64);  sw += __shfl_xor(sw, 32, 64);

    if (lane < 16) {
        float4 res; res.x = sx; res.y = sy; res.z = sz; res.w = sw;
        *(float4*)(out + (u * NA + a) * NV + (sub << 2)) = res;  // 256B coalesced
    }
}

__global__ __launch_bounds__(512, 8)
void siddon_fused(const float* __restrict__ vol, float* __restrict__ out)
{
    __shared__ int2 sEnt[TILE][NENT];  // .x = BYTE offset of vol row, .y = weight bits

    const int tid  = threadIdx.x;
    const int wid  = tid >> 6;         // wave index in block
    const int lane = tid & 63;
    const int bid  = blockIdx.x;

    int2* __restrict__ myRow = &sEnt[wid][0];

    const int ray0 = bid * TILE + wid;             // rays 0..8191
    do_ray(vol, out, myRow, ray0, lane);

    // leftover rays 8192..8639: one per block (bid<448), on a wave chosen so
    // the two extras per CU land on different SIMDs.
    if (bid < NEXTRA && wid == ((bid + (bid >> 8)) & 7)) {
        do_ray(vol, out, myRow, NBLK * TILE + bid, lane);
    }
}

extern "C" void kernel_launch(void* const* d_in, const int* in_sizes, int n_in,
                              void* d_out, int out_size, void* d_ws, size_t ws_size,
                              hipStream_t stream) {
    const float* vol = (const float*)d_in[0];
    float* out = (float*)d_out;
    hipLaunchKernelGGL(siddon_fused, dim3(NBLK), dim3(512), 0, stream, vol, out);
}